// Round 7
// baseline (1877.255 us; speedup 1.0000x reference)
//
#include <hip/hip_runtime.h>
#include <math.h>

#define BB 64
#define TT 577
#define DD 768
#define DENS 519   // int(577*0.9)
#define NSKIP 58
#define NROWS (BB * TT)   // 36928

#define PGRID 2048
#define PWAVES (PGRID * 4)   // 8192 waves, co-resident under cooperative launch

typedef float vf4 __attribute__((ext_vector_type(4)));

// Order-preserving map: double bits -> u64 (lexicographic == numeric order).
__device__ inline unsigned long long key_of(double z) {
    long long b = __double_as_longlong(z);
    return (b < 0) ? ~(unsigned long long)b
                   : ((unsigned long long)b | 0x8000000000000000ULL);
}
__device__ inline double key_inv(unsigned long long k) {
    long long b = (k >> 63) ? (long long)(k & 0x7fffffffffffffffULL)
                            : ~(long long)k;
    return __longlong_as_double(b);
}

// ---------------------------------------------------------------------------
// Cooperative pipeline kernel. Phase 1: grid-stride keys (R0 k_prob math,
// w hoisted — identical per-lane FP order). Each completed row does a
// release-atomicAdd on its batch counter. Phase 2: grid-stride rank+scatter
// (R0 k_rankscatter body verbatim); waits only for its row's batch via
// relaxed spin (lane 0) + wave-wide acquire load. No grid.sync: scatter
// writes of ready batches overlap key reads of later batches -> HBM read
// and write streams run concurrently instead of serially.
// Deadlock-free: cooperative launch guarantees all 2048 blocks co-resident,
// so every batch's key producers are always running.
// __launch_bounds__(256,8): 8 waves/EU -> VGPR<=64 -> 8 blocks/CU -> 2048
// blocks co-resident. Summary stays in separate k_soft (register-lean copy
// path — round-6 lesson).
// ---------------------------------------------------------------------------
__global__ __launch_bounds__(256, 8) void k_pipe(
        const float* __restrict__ x, const float* __restrict__ w,
        const float* __restrict__ bias,
        unsigned long long* __restrict__ keys,
        unsigned int* __restrict__ done,
        int* __restrict__ skip_src,
        unsigned long long* __restrict__ skip_key,
        float* __restrict__ out) {
    const int gwave = (int)((blockIdx.x * 256 + threadIdx.x) >> 6);
    const int lane  = threadIdx.x & 63;

    // ---- phase 1: keys + per-batch release counters ----
    {
        const float4* w4 = (const float4*)w;
        const float4 wv0 = w4[lane];
        const float4 wv1 = w4[lane + 64];
        const float4 wv2 = w4[lane + 128];
        const double bz = (double)bias[0];
        for (int r = gwave; r < NROWS; r += PWAVES) {
            const float4* r4 = (const float4*)(x + (size_t)r * DD);
            float4 a0 = r4[lane];
            float4 a1 = r4[lane + 64];
            float4 a2 = r4[lane + 128];
            double acc = 0.0;
            acc += (double)a0.x * (double)wv0.x + (double)a0.y * (double)wv0.y
                 + (double)a0.z * (double)wv0.z + (double)a0.w * (double)wv0.w;
            acc += (double)a1.x * (double)wv1.x + (double)a1.y * (double)wv1.y
                 + (double)a1.z * (double)wv1.z + (double)a1.w * (double)wv1.w;
            acc += (double)a2.x * (double)wv2.x + (double)a2.y * (double)wv2.y
                 + (double)a2.z * (double)wv2.z + (double)a2.w * (double)wv2.w;
#pragma unroll
            for (int off = 32; off; off >>= 1)
                acc += __shfl_down(acc, off, 64);
            if (lane == 0) {
                keys[r] = key_of(acc + bz);
                __hip_atomic_fetch_add(&done[r / TT], 1u,
                                       __ATOMIC_RELEASE, __HIP_MEMORY_SCOPE_AGENT);
            }
        }
    }

    // ---- phase 2: rank + scatter (waits per-batch, not grid-wide) ----
    for (int r = gwave; r < NROWS; r += PWAVES) {
        int b = r / TT;
        int i = r - b * TT;
        if (lane == 0) {
            while (__hip_atomic_load(&done[b], __ATOMIC_RELAXED,
                                     __HIP_MEMORY_SCOPE_AGENT) < TT)
                __builtin_amdgcn_s_sleep(2);
        }
        // wave-wide acquire: orders all following loads, invalidates caches
        (void)__hip_atomic_load(&done[b], __ATOMIC_ACQUIRE,
                                __HIP_MEMORY_SCOPE_AGENT);

        const unsigned long long* kb = keys + b * TT;
        unsigned long long ki = kb[i];
        int rd = 0, ra = 0;
#pragma unroll
        for (int c = 0; c < 10; ++c) {
            int j = lane + 64 * c;
            if (j < TT) {
                unsigned long long kj = kb[j];
                bool tie = (kj == ki) & (j < i);
                rd += ((kj > ki) | tie) ? 1 : 0;
                ra += ((kj < ki) | tie) ? 1 : 0;
            }
        }
        unsigned long long pack = ((unsigned long long)(unsigned)rd << 32) | (unsigned)ra;
#pragma unroll
        for (int off = 32; off; off >>= 1)
            pack += __shfl_xor(pack, off, 64);      // all lanes get totals
        int r_desc = (int)(pack >> 32);
        int r_asc  = (int)(pack & 0xffffffffu);

        size_t dst;
        if (r_desc < DENS) {
            dst = (size_t)(b * DENS + r_desc) * DD;
        } else {
            dst = (size_t)BB * DENS * DD + (size_t)(b * NSKIP + r_asc) * DD;
            if (lane == 0) {
                skip_src[b * NSKIP + r_asc] = i;
                skip_key[b * NSKIP + r_asc] = ki;
            }
        }
        const vf4* s4 = (const vf4*)(x + (size_t)r * DD);
        vf4* d4 = (vf4*)(out + dst);
#pragma unroll
        for (int c = 0; c < 3; ++c) {
            vf4 v = s4[lane + 64 * c];
            __builtin_nontemporal_store(v, &d4[lane + 64 * c]);
        }
    }
}

// ---------------------------------------------------------------------------
// Fallback kernels: the reproducibly-best round-0 pipeline, verbatim.
// ---------------------------------------------------------------------------
__global__ __launch_bounds__(256) void k_prob(const float* __restrict__ x,
                                              const float* __restrict__ w,
                                              const float* __restrict__ bias,
                                              unsigned long long* __restrict__ keys) {
    int wave = (int)((blockIdx.x * blockDim.x + threadIdx.x) >> 6);
    int lane = threadIdx.x & 63;
    if (wave >= NROWS) return;
    const float4* r4 = (const float4*)(x + (size_t)wave * DD);
    const float4* w4 = (const float4*)w;
    double acc = 0.0;
#pragma unroll
    for (int i = 0; i < 3; ++i) {
        float4 a = r4[lane + 64 * i];
        float4 b = w4[lane + 64 * i];
        acc += (double)a.x * (double)b.x + (double)a.y * (double)b.y
             + (double)a.z * (double)b.z + (double)a.w * (double)b.w;
    }
#pragma unroll
    for (int off = 32; off; off >>= 1)
        acc += __shfl_down(acc, off, 64);
    if (lane == 0) keys[wave] = key_of(acc + (double)bias[0]);
}

__global__ __launch_bounds__(256) void k_rankscatter(const float* __restrict__ x,
                                                     const unsigned long long* __restrict__ keys,
                                                     int* __restrict__ skip_src,
                                                     unsigned long long* __restrict__ skip_key,
                                                     float* __restrict__ out) {
    int wave = (int)((blockIdx.x * blockDim.x + threadIdx.x) >> 6);
    int lane = threadIdx.x & 63;
    if (wave >= NROWS) return;
    int b = wave / TT;
    int i = wave - b * TT;
    const unsigned long long* kb = keys + b * TT;
    unsigned long long ki = kb[i];
    int rd = 0, ra = 0;
#pragma unroll
    for (int c = 0; c < 10; ++c) {
        int j = lane + 64 * c;
        if (j < TT) {
            unsigned long long kj = kb[j];
            bool tie = (kj == ki) & (j < i);
            rd += ((kj > ki) | tie) ? 1 : 0;
            ra += ((kj < ki) | tie) ? 1 : 0;
        }
    }
    unsigned long long pack = ((unsigned long long)(unsigned)rd << 32) | (unsigned)ra;
#pragma unroll
    for (int off = 32; off; off >>= 1)
        pack += __shfl_xor(pack, off, 64);
    int r_desc = (int)(pack >> 32);
    int r_asc  = (int)(pack & 0xffffffffu);
    size_t dst;
    if (r_desc < DENS) {
        dst = (size_t)(b * DENS + r_desc) * DD;
    } else {
        dst = (size_t)BB * DENS * DD + (size_t)(b * NSKIP + r_asc) * DD;
        if (lane == 0) {
            skip_src[b * NSKIP + r_asc] = i;
            skip_key[b * NSKIP + r_asc] = ki;
        }
    }
    const vf4* s4 = (const vf4*)(x + ((size_t)b * TT + i) * DD);
    vf4* d4 = (vf4*)(out + dst);
#pragma unroll
    for (int c = 0; c < 3; ++c) {
        vf4 v = s4[lane + 64 * c];
        __builtin_nontemporal_store(v, &d4[lane + 64 * c]);
    }
}

__global__ __launch_bounds__(768) void k_soft(const float* __restrict__ x,
                                              const int* __restrict__ skip_src,
                                              const unsigned long long* __restrict__ skip_key,
                                              float* __restrict__ summary) {
    __shared__ float wsh[NSKIP];
    __shared__ int   ssh[NSKIP];
    int b = blockIdx.x;
    int t = threadIdx.x;
    if (t < NSKIP) ssh[t] = skip_src[b * NSKIP + t];
    if (t < 64) {
        double pv = -1.0e300;
        if (t < NSKIP) {
            double z = key_inv(skip_key[b * NSKIP + t]);
            pv = 1.0 / (1.0 + exp(-z));
        }
        double m = pv;
#pragma unroll
        for (int off = 32; off; off >>= 1) {
            double o = __shfl_down(m, off, 64);
            m = (o > m) ? o : m;
        }
        m = __shfl(m, 0, 64);
        double e = (t < NSKIP) ? exp(pv - m) : 0.0;
        double s = e;
#pragma unroll
        for (int off = 32; off; off >>= 1)
            s += __shfl_down(s, off, 64);
        s = __shfl(s, 0, 64);
        if (t < NSKIP) wsh[t] = (float)(e / s);
    }
    __syncthreads();
    float acc = 0.f;
    const float* xb = x + (size_t)b * TT * DD;
    for (int k = 0; k < NSKIP; ++k)
        acc += wsh[k] * xb[(size_t)ssh[k] * DD + t];
    summary[(size_t)b * DD + t] = acc;
}

extern "C" void kernel_launch(void* const* d_in, const int* in_sizes, int n_in,
                              void* d_out, int out_size, void* d_ws, size_t ws_size,
                              hipStream_t stream) {
    const float* x    = (const float*)d_in[0];
    const float* w    = (const float*)d_in[1];
    const float* bias = (const float*)d_in[2];
    float* out = (float*)d_out;
    char* ws = (char*)d_ws;

    unsigned long long* keys = (unsigned long long*)ws;              // 295424 B
    int* skip_src = (int*)(ws + 295424);                             // 14848 B
    unsigned long long* skip_key =
        (unsigned long long*)(ws + 295424 + 14848);                  // 29696 B
    unsigned int* done = (unsigned int*)(ws + 295424 + 14848 + 29696); // 256 B

    // ws is poisoned between iterations -> counters must be zeroed.
    hipMemsetAsync(done, 0, BB * sizeof(unsigned int), stream);

    void* args[] = { (void*)&x, (void*)&w, (void*)&bias, (void*)&keys,
                     (void*)&done, (void*)&skip_src, (void*)&skip_key, (void*)&out };
    hipError_t err = hipLaunchCooperativeKernel((const void*)k_pipe,
                                                dim3(PGRID), dim3(256),
                                                args, 0u, stream);
    if (err == hipSuccess) {
        k_soft<<<BB, 768, 0, stream>>>(x, skip_src, skip_key,
                                       out + (size_t)BB * (DENS + NSKIP) * DD);
    } else {
        // Fallback: reproducibly-best 3-kernel pipeline (round-0).
        const int nblk = NROWS / 4;
        k_prob<<<nblk, 256, 0, stream>>>(x, w, bias, keys);
        k_rankscatter<<<nblk, 256, 0, stream>>>(x, keys, skip_src, skip_key, out);
        k_soft<<<BB, 768, 0, stream>>>(x, skip_src, skip_key,
                                       out + (size_t)BB * (DENS + NSKIP) * DD);
    }
}